// Round 11
// baseline (335.812 us; speedup 1.0000x reference)
//
#include <hip/hip_runtime.h>
#include <hip/hip_bf16.h>
#include <stdint.h>

// Problem: B=4, N=2048, C=1024, H=16, D=64.
// Device dtypes: ALL inputs fp32, output fp32. Internal: bf16 MFMA, fp32 accum.
// x @ Wqkv.T -> RoPE(q,k) -> per-(b,h) softmax(q k^T /8 + mask) v -> @ Wproj.T + b

typedef __bf16 bf16;
typedef __bf16 bf16x4 __attribute__((ext_vector_type(4)));
typedef __bf16 bf16x8 __attribute__((ext_vector_type(8)));
typedef float  f32x4  __attribute__((ext_vector_type(4)));
typedef float  f32x16 __attribute__((ext_vector_type(16)));
typedef int    int4v  __attribute__((ext_vector_type(4)));

#define MFMA16(a, b, c) __builtin_amdgcn_mfma_f32_16x16x32_bf16((a), (b), (c), 0, 0, 0)
#define MFMA32(a, b, c) __builtin_amdgcn_mfma_f32_32x32x16_bf16((a), (b), (c), 0, 0, 0)

__device__ __forceinline__ bf16x4 cvt4s(float a, float b, float c, float d) {
  bf16x4 r;
  r[0] = (bf16)a; r[1] = (bf16)b; r[2] = (bf16)c; r[3] = (bf16)d;
  return r;
}
__device__ __forceinline__ bf16x8 cvt8(f32x4 a, f32x4 b) {
  bf16x8 r;
  r[0] = (bf16)a[0]; r[1] = (bf16)a[1]; r[2] = (bf16)a[2]; r[3] = (bf16)a[3];
  r[4] = (bf16)b[0]; r[5] = (bf16)b[1]; r[6] = (bf16)b[2]; r[7] = (bf16)b[3];
  return r;
}
__device__ __forceinline__ void gload16(const void* g, void* l) {
  __builtin_amdgcn_global_load_lds((const __attribute__((address_space(1))) void*)g,
                                   (__attribute__((address_space(3))) void*)l, 16, 0, 0);
}

// ---------------------------------------------------------------------------
// fp32 -> bf16 bulk convert; optional scale (mask * log2e).
// ---------------------------------------------------------------------------
__global__ __launch_bounds__(256)
void cvt_k(const float* __restrict__ W, bf16* __restrict__ Wb, float scale)
{
  const size_t i = ((size_t)blockIdx.x * 256 + threadIdx.x) * 8;
  const float* p = W + i;
  f32x4 a = *(const f32x4*)p * scale;
  f32x4 b = *(const f32x4*)(p + 4) * scale;
  *(bf16x8*)(Wb + i) = cvt8(a, b);
}

// ---------------------------------------------------------------------------
// GEMM, m97 structure: C[m][n] = sum_k A[m][k]*B[n][k]; A,B bf16, both staged
// via global_load_lds width-16. MODE selects epilogue:
//   0: scatter Q,K -> [BH][N][64] bf16, V -> VT [BH][64][N] bf16.
//   1: + bias -> out fp32 [8192][1024].
// ---------------------------------------------------------------------------
template<int MODE>
__global__ __launch_bounds__(256)
void gemm_bt(const bf16* __restrict__ A, const bf16* __restrict__ B,
             void* __restrict__ O0, bf16* __restrict__ O1, bf16* __restrict__ O2,
             const float* __restrict__ bias)
{
  constexpr int K = 1024;
  __shared__ __attribute__((aligned(16))) bf16 As[128 * 64];
  __shared__ __attribute__((aligned(16))) bf16 Bs[128 * 64];
  const int tid = threadIdx.x, lane = tid & 63, wid = tid >> 6;
  const int m0 = blockIdx.x * 128, n0 = blockIdx.y * 128;
  const int wm = (wid >> 1) * 64, wn = (wid & 1) * 64;
  const int l15 = lane & 15, lg = lane >> 4;

  f32x4 acc[4][4] = {};

  for (int k0 = 0; k0 < K; k0 += 64) {
#pragma unroll
    for (int c = 0; c < 4; ++c) {
      const int seg = wid * 4 + c;
      const int o = seg * 1024 + lane * 16;   // byte offset in 16KB tile
      const int row = o >> 7, colb = o & 127; // 128B per row (64 bf16)
      gload16((const char*)B + (((size_t)(n0 + row) * K + k0) << 1) + colb,
              (char*)Bs + seg * 1024);
      gload16((const char*)A + (((size_t)(m0 + row) * K + k0) << 1) + colb,
              (char*)As + seg * 1024);
    }
    __syncthreads();

    bf16x8 af[4][2], bb[4][2];
#pragma unroll
    for (int i = 0; i < 4; ++i)
#pragma unroll
      for (int kk = 0; kk < 2; ++kk) {
        af[i][kk] = *(const bf16x8*)(As + (wm + i * 16 + l15) * 64 + kk * 32 + lg * 8);
        bb[i][kk] = *(const bf16x8*)(Bs + (wn + i * 16 + l15) * 64 + kk * 32 + lg * 8);
      }
#pragma unroll
    for (int mi = 0; mi < 4; ++mi)
#pragma unroll
      for (int ni = 0; ni < 4; ++ni)
#pragma unroll
        for (int kk = 0; kk < 2; ++kk)
          acc[mi][ni] = MFMA16(af[mi][kk], bb[ni][kk], acc[mi][ni]);
    __syncthreads();
  }

#pragma unroll
  for (int mi = 0; mi < 4; ++mi)
#pragma unroll
    for (int ni = 0; ni < 4; ++ni)
#pragma unroll
      for (int r = 0; r < 4; ++r) {
        const int row = m0 + wm + mi * 16 + lg * 4 + r;
        const int col = n0 + wn + ni * 16 + l15;
        float v = acc[mi][ni][r];
        if (MODE == 0) {
          const int s = col >> 10, h = (col >> 6) & 15, d = col & 63;
          const int b = row >> 11, n = row & 2047;
          const bf16 bv = (bf16)v;
          if (s == 0)
            ((bf16*)O0)[(((size_t)(b * 16 + h) * 2048) + n) * 64 + d] = bv;
          else if (s == 1)
            O1[(((size_t)(b * 16 + h) * 2048) + n) * 64 + d] = bv;
          else
            O2[(((size_t)(b * 16 + h) * 64) + d) * 2048 + n] = bv;
        } else {
          ((float*)O0)[(size_t)row * 1024 + col] = v + bias[col];
        }
      }
}

// ---------------------------------------------------------------------------
// RoPE in place on Q and K ([BH][N][64] bf16). cos/sin fp32 [B][N][32].
// Q additionally pre-scaled by SCALE*log2e so attention softmax is exp2(s).
// ---------------------------------------------------------------------------
__global__ __launch_bounds__(256)
void rope_k(bf16* __restrict__ Q, bf16* __restrict__ K,
            const float* __restrict__ C, const float* __restrict__ S)
{
  constexpr float SL = 0.125f * 1.4426950408889634f;
  const int gid = blockIdx.x * 256 + threadIdx.x;
  const int part = gid & 3;
  const int rowid = gid >> 2;
  const int n = rowid & 2047;
  const int b = rowid >> 15;
  const size_t cbase = ((size_t)(b * 2048 + n)) * 32 + part * 8;

  float cf[8], sf[8];
  *(f32x4*)cf = *(const f32x4*)(C + cbase);
  *(f32x4*)(cf + 4) = *(const f32x4*)(C + cbase + 4);
  *(f32x4*)sf = *(const f32x4*)(S + cbase);
  *(f32x4*)(sf + 4) = *(const f32x4*)(S + cbase + 4);

  bf16* qp = Q + (size_t)rowid * 64 + part * 16;
  bf16* kp = K + (size_t)rowid * 64 + part * 16;
  __attribute__((aligned(16))) bf16 buf[16];

  *(int4v*)buf = *(const int4v*)qp;
  *(int4v*)(buf + 8) = *(const int4v*)(qp + 8);
#pragma unroll
  for (int j = 0; j < 8; ++j) {
    const float t0 = (float)buf[2 * j], t1 = (float)buf[2 * j + 1];
    buf[2 * j]     = (bf16)((t0 * cf[j] - t1 * sf[j]) * SL);
    buf[2 * j + 1] = (bf16)((t0 * sf[j] + t1 * cf[j]) * SL);
  }
  *(int4v*)qp = *(int4v*)buf;
  *(int4v*)(qp + 8) = *(int4v*)(buf + 8);

  *(int4v*)buf = *(const int4v*)kp;
  *(int4v*)(buf + 8) = *(const int4v*)(kp + 8);
#pragma unroll
  for (int j = 0; j < 8; ++j) {
    const float t0 = (float)buf[2 * j], t1 = (float)buf[2 * j + 1];
    buf[2 * j]     = (bf16)(t0 * cf[j] - t1 * sf[j]);
    buf[2 * j + 1] = (bf16)(t0 * sf[j] + t1 * cf[j]);
  }
  *(int4v*)kp = *(int4v*)buf;
  *(int4v*)(kp + 8) = *(int4v*)(buf + 8);
}

// ---------------------------------------------------------------------------
// Flash attention v9: round-10 core (mfma_32x32x16, swapped QK^T, mask as
// MFMA C-init, exp2 softmax, in-register P via cvt_pk+permlane, setprio)
// + T14 ASYNC-STAGE SPLIT with LDS DOUBLE-BUFFER: one barrier per kv-tile;
// next tile's K/V+mask loads are issued right after the barrier and land in
// registers while this tile's QK^T/softmax/PV runs; the reg->LDS write of
// tile t+1 goes to the buffer last read at t-1 (safe), just before the
// barrier. Removes the per-tile vmcnt(0)-at-barrier HBM bubble.
// MM=1: mask bf16*log2e (ws-cached); MM=0: fp32 mask fallback.
// ---------------------------------------------------------------------------
template<int MM>
__global__ __launch_bounds__(256, 4)
void attn_k(const bf16* __restrict__ Q, const bf16* __restrict__ K,
            const bf16* __restrict__ VT, const void* __restrict__ Mv,
            bf16* __restrict__ O)
{
  constexpr float LOG2E = 1.4426950408889634f;
  constexpr int NT = 32;
  // two K/V buffer sets of 8192 bf16 each; epilogue overlays [0, 9216)
  __shared__ __attribute__((aligned(16))) bf16 SH[16384];

  const int tid = threadIdx.x, lane = tid & 63, w = tid >> 6;
  const int bh = blockIdx.x;
  const int q0 = blockIdx.y * 128;
  const int b = bh >> 4, h = bh & 15;
  const int l31 = lane & 31, hi = lane >> 5;
  const int swz = (l31 & 7) << 3;

  const bf16* Qb = Q + (size_t)bh * 2048 * 64;
  const bf16* Kb = K + (size_t)bh * 2048 * 64;
  const bf16* Vb = VT + (size_t)bh * 64 * 2048;
  const float* Mqf = (const float*)Mv + (size_t)(q0 + w * 32 + l31) * 2048;
  const bf16*  Mqb = (const bf16*)Mv  + (size_t)(q0 + w * 32 + l31) * 2048;

  // per-thread staging geometry (same both iterations): 512 slots = 64 rows x 8 groups
  const int srow0 = tid >> 3,          sg8 = (tid & 7) * 8;
  const int srow1 = (256 + tid) >> 3;  // second slot, same g8
  const int ssc = sg8 ^ 0;             // swizzle applied per-row below

  bf16x8 qf[4];
  {
    const bf16* qr = Qb + (size_t)(q0 + w * 32 + l31) * 64 + 8 * hi;
#pragma unroll
    for (int j = 0; j < 4; ++j) qf[j] = *(const bf16x8*)(qr + 16 * j);
  }
  (void)ssc;

  f32x16 o[2] = {{0,0,0,0,0,0,0,0,0,0,0,0,0,0,0,0},
                 {0,0,0,0,0,0,0,0,0,0,0,0,0,0,0,0}};
  float li = 0.f;

  // ---- prologue: stage tile 0 into buf0, prefetch mask(0) ----
  int4v kreg[2], vreg[2];
  kreg[0] = *(const int4v*)(Kb + (size_t)srow0 * 64 + sg8);
  kreg[1] = *(const int4v*)(Kb + (size_t)srow1 * 64 + sg8);
  vreg[0] = *(const int4v*)(Vb + (size_t)srow0 * 2048 + sg8);
  vreg[1] = *(const int4v*)(Vb + (size_t)srow1 * 2048 + sg8);

  f32x4  mkf_cur[2][4], mkf_nxt[2][4];
  bf16x4 mkb_cur[2][4], mkb_nxt[2][4];
#pragma unroll
  for (int sub = 0; sub < 2; ++sub)
#pragma unroll
    for (int rg = 0; rg < 4; ++rg) {
      if (MM == 0)
        mkf_cur[sub][rg] = *(const f32x4*)(Mqf + 32 * sub + 8 * rg + 4 * hi);
      else
        mkb_cur[sub][rg] = *(const bf16x4*)(Mqb + 32 * sub + 8 * rg + 4 * hi);
    }

  {
    bf16* Kt = SH;
    bf16* Vt = SH + 4096;
    *(int4v*)(Kt + srow0 * 64 + (sg8 ^ ((srow0 & 7) << 3))) = kreg[0];
    *(int4v*)(Kt + srow1 * 64 + (sg8 ^ ((srow1 & 7) << 3))) = kreg[1];
    *(int4v*)(Vt + srow0 * 64 + (sg8 ^ ((srow0 & 7) << 3))) = vreg[0];
    *(int4v*)(Vt + srow1 * 64 + (sg8 ^ ((srow1 & 7) << 3))) = vreg[1];
  }
  __syncthreads();

  for (int t = 0; t < NT; ++t) {
    const int kv0 = t * 64;
    bf16* Kt = SH + (t & 1) * 8192;
    bf16* Vt = Kt + 4096;

    // issue next tile's loads (K/V first, then mask) -- land during compute
    if (t + 1 < NT) {
      const int kvn = kv0 + 64;
      kreg[0] = *(const int4v*)(Kb + (size_t)(kvn + srow0) * 64 + sg8);
      kreg[1] = *(const int4v*)(Kb + (size_t)(kvn + srow1) * 64 + sg8);
      vreg[0] = *(const int4v*)(Vb + (size_t)srow0 * 2048 + kvn + sg8);
      vreg[1] = *(const int4v*)(Vb + (size_t)srow1 * 2048 + kvn + sg8);
#pragma unroll
      for (int sub = 0; sub < 2; ++sub)
#pragma unroll
        for (int rg = 0; rg < 4; ++rg) {
          if (MM == 0)
            mkf_nxt[sub][rg] = *(const f32x4*)(Mqf + kvn + 32 * sub + 8 * rg + 4 * hi);
          else
            mkb_nxt[sub][rg] = *(const bf16x4*)(Mqb + kvn + 32 * sub + 8 * rg + 4 * hi);
        }
    }

#pragma unroll
    for (int sub = 0; sub < 2; ++sub) {
      // S^T = K Q'^T with C initialized to mask*log2e (Q' pre-scaled)
      f32x16 s;
#pragma unroll
      for (int rg = 0; rg < 4; ++rg)
#pragma unroll
        for (int i = 0; i < 4; ++i)
          s[4 * rg + i] = (MM == 0) ? mkf_cur[sub][rg][i] * LOG2E
                                    : (float)mkb_cur[sub][rg][i];
      __builtin_amdgcn_s_setprio(1);
#pragma unroll
      for (int j = 0; j < 4; ++j) {
        const bf16x8 kf = *(const bf16x8*)(
            Kt + (sub * 32 + l31) * 64 + ((16 * j + 8 * hi) ^ swz));
        s = MFMA32(kf, qf[j], s);
      }
      __builtin_amdgcn_s_setprio(0);

      // softmax: p = exp2(s); row-sum 16 local + 1 shfl
      float rs = 0.f;
#pragma unroll
      for (int e = 0; e < 16; ++e) {
        const float p = __builtin_exp2f(s[e]);
        s[e] = p;
        rs += p;
      }
      rs += __shfl_xor(rs, 32);
      li += rs;

      // T12: P -> bf16 in-register; permlane32_swap builds PV B-fragments
      uint32_t pk0, pk1, pk2, pk3, pk4, pk5, pk6, pk7;
      asm("v_cvt_pk_bf16_f32 %0, %1, %2" : "=v"(pk0) : "v"(s[0]),  "v"(s[1]));
      asm("v_cvt_pk_bf16_f32 %0, %1, %2" : "=v"(pk1) : "v"(s[2]),  "v"(s[3]));
      asm("v_cvt_pk_bf16_f32 %0, %1, %2" : "=v"(pk2) : "v"(s[4]),  "v"(s[5]));
      asm("v_cvt_pk_bf16_f32 %0, %1, %2" : "=v"(pk3) : "v"(s[6]),  "v"(s[7]));
      asm("v_cvt_pk_bf16_f32 %0, %1, %2" : "=v"(pk4) : "v"(s[8]),  "v"(s[9]));
      asm("v_cvt_pk_bf16_f32 %0, %1, %2" : "=v"(pk5) : "v"(s[10]), "v"(s[11]));
      asm("v_cvt_pk_bf16_f32 %0, %1, %2" : "=v"(pk6) : "v"(s[12]), "v"(s[13]));
      asm("v_cvt_pk_bf16_f32 %0, %1, %2" : "=v"(pk7) : "v"(s[14]), "v"(s[15]));
      asm("v_permlane32_swap_b32 %0, %1" : "+v"(pk0), "+v"(pk2));
      asm("v_permlane32_swap_b32 %0, %1" : "+v"(pk1), "+v"(pk3));
      asm("v_permlane32_swap_b32 %0, %1" : "+v"(pk4), "+v"(pk6));
      asm("v_permlane32_swap_b32 %0, %1" : "+v"(pk5), "+v"(pk7));
      uint32_t pau[2][4] = {{pk0, pk1, pk2, pk3}, {pk4, pk5, pk6, pk7}};
      bf16x8 pa[2];
      __builtin_memcpy(&pa[0], pau[0], 16);
      __builtin_memcpy(&pa[1], pau[1], 16);

      // PV: O^T[d'][q] += V^T[d'][kv] P^T[kv][q]
      __builtin_amdgcn_s_setprio(1);
#pragma unroll
      for (int kh = 0; kh < 2; ++kh)
#pragma unroll
        for (int dblk = 0; dblk < 2; ++dblk) {
          const bf16x8 vf = *(const bf16x8*)(
              Vt + (dblk * 32 + l31) * 64 + ((sub * 32 + kh * 16 + 8 * hi) ^ swz));
          o[dblk] = MFMA32(vf, pa[kh], o[dblk]);
        }
      __builtin_amdgcn_s_setprio(0);
    }

    // write tile t+1 into the other buffer (compiler waits counted vmcnt for
    // kreg/vreg only); rotate mask regs.
    if (t + 1 < NT) {
      bf16* Ktn = SH + ((t + 1) & 1) * 8192;
      bf16* Vtn = Ktn + 4096;
      *(int4v*)(Ktn + srow0 * 64 + (sg8 ^ ((srow0 & 7) << 3))) = kreg[0];
      *(int4v*)(Ktn + srow1 * 64 + (sg8 ^ ((srow1 & 7) << 3))) = kreg[1];
      *(int4v*)(Vtn + srow0 * 64 + (sg8 ^ ((srow0 & 7) << 3))) = vreg[0];
      *(int4v*)(Vtn + srow1 * 64 + (sg8 ^ ((srow1 & 7) << 3))) = vreg[1];
#pragma unroll
      for (int sub = 0; sub < 2; ++sub)
#pragma unroll
        for (int rg = 0; rg < 4; ++rg) {
          if (MM == 0) mkf_cur[sub][rg] = mkf_nxt[sub][rg];
          else         mkb_cur[sub][rg] = mkb_nxt[sub][rg];
        }
    }
    __syncthreads();
  }

  // epilogue: normalize (lane-local), transpose via LDS, b128 stores.
  const float inv = 1.f / li;
  bf16* ow = SH + w * 2304;
#pragma unroll
  for (int dblk = 0; dblk < 2; ++dblk)
#pragma unroll
    for (int rg = 0; rg < 4; ++rg)
      *(bf16x4*)(ow + l31 * 72 + dblk * 32 + 8 * rg + 4 * hi) =
          cvt4s(o[dblk][4 * rg] * inv, o[dblk][4 * rg + 1] * inv,
                o[dblk][4 * rg + 2] * inv, o[dblk][4 * rg + 3] * inv);
  asm volatile("s_waitcnt lgkmcnt(0)" ::: "memory");
  __builtin_amdgcn_sched_barrier(0);
#pragma unroll
  for (int p = 0; p < 4; ++p) {
    const int row = p * 8 + (lane >> 3);
    const int n = q0 + w * 32 + row;
    const int4v v = *(const int4v*)(ow + row * 72 + (lane & 7) * 8);
    *(int4v*)(O + ((size_t)b * 2048 + n) * 1024 + h * 64 + (lane & 7) * 8) = v;
  }
}

// ---------------------------------------------------------------------------
extern "C" void kernel_launch(void* const* d_in, const int* in_sizes, int n_in,
                              void* d_out, int out_size, void* d_ws, size_t ws_size,
                              hipStream_t stream)
{
  (void)in_sizes; (void)n_in; (void)out_size;
  const float* x     = (const float*)d_in[0];
  const float* fcos  = (const float*)d_in[1];
  const float* fsin  = (const float*)d_in[2];
  const float* mask  = (const float*)d_in[3];
  const float* wqkv  = (const float*)d_in[4];
  const float* wproj = (const float*)d_in[5];
  const float* bproj = (const float*)d_in[6];
  float* out = (float*)d_out;

  const size_t SZ  = (size_t)64 * 2048 * 64 * 2;           // 16.78 MB
  const size_t WQB = (size_t)3072 * 1024 * 2;              // 6.29 MB
  const size_t WPB = (size_t)1024 * 1024 * 2;              // 2.10 MB
  const size_t MKB = (size_t)2048 * 2048 * 2;              // 8.39 MB (bf16 mask)
  const size_t BASE = 4 * SZ + WQB + WPB;                  // 75.5 MB (proven)
  if (ws_size < BASE) return;                              // fail loudly
  char* ws = (char*)d_ws;
  bf16* Qr  = (bf16*)(ws);
  bf16* Kr  = (bf16*)(ws + SZ);
  bf16* VT  = (bf16*)(ws + 2 * SZ);
  bf16* Ob  = (bf16*)(ws + 3 * SZ);   // doubles as bf16(x) before attn runs
  bf16* Wqb = (bf16*)(ws + 4 * SZ);
  bf16* Wpb = (bf16*)(ws + 4 * SZ + WQB);
  bf16* Mb  = (bf16*)(ws + BASE);
  const bool useMb = (ws_size >= BASE + MKB);
  constexpr float LOG2E = 1.4426950408889634f;
  bf16* Xb = Ob;  // x-bf16 lives in the Ob slot (dead until attn)

  cvt_k<<<4096, 256, 0, stream>>>(x, Xb, 1.0f);
  cvt_k<<<1536, 256, 0, stream>>>(wqkv, Wqb, 1.0f);
  cvt_k<<<512, 256, 0, stream>>>(wproj, Wpb, 1.0f);
  if (useMb) cvt_k<<<2048, 256, 0, stream>>>(mask, Mb, LOG2E);
  gemm_bt<0><<<dim3(64, 24), 256, 0, stream>>>(Xb, Wqb, Qr, Kr, VT, nullptr);
  rope_k<<<2048, 256, 0, stream>>>(Qr, Kr, fcos, fsin);
  if (useMb)
    attn_k<1><<<dim3(64, 16), 256, 0, stream>>>(Qr, Kr, VT, Mb, Ob);
  else
    attn_k<0><<<dim3(64, 16), 256, 0, stream>>>(Qr, Kr, VT, mask, Ob);
  gemm_bt<1><<<dim3(64, 8), 256, 0, stream>>>(Ob, Wpb, out, nullptr, nullptr, bproj);
}

// Round 12
// 295.926 us; speedup vs baseline: 1.1348x; 1.1348x over previous
//
#include <hip/hip_runtime.h>
#include <hip/hip_bf16.h>
#include <stdint.h>

// Problem: B=4, N=2048, C=1024, H=16, D=64.
// Device dtypes: ALL inputs fp32, output fp32. Internal: bf16 MFMA, fp32 accum.
// x @ Wqkv.T -> RoPE(q,k) -> per-(b,h) softmax(q k^T /8 + mask) v -> @ Wproj.T + b
//
// K in ws is stored D-SWIZZLED:  ws_K[n][x]  = K[n][x ^ ((n&7)<<3)]
// VT in ws is stored N-SWIZZLED: ws_VT[d][m] = VT[d][(m&~63) | ((m&63)^((d&7)<<3))]
// so attn can stage via linear global_load_lds and read with the XOR swizzle.

typedef __bf16 bf16;
typedef __bf16 bf16x4 __attribute__((ext_vector_type(4)));
typedef __bf16 bf16x8 __attribute__((ext_vector_type(8)));
typedef float  f32x4  __attribute__((ext_vector_type(4)));
typedef float  f32x16 __attribute__((ext_vector_type(16)));
typedef int    int4v  __attribute__((ext_vector_type(4)));

#define MFMA16(a, b, c) __builtin_amdgcn_mfma_f32_16x16x32_bf16((a), (b), (c), 0, 0, 0)
#define MFMA32(a, b, c) __builtin_amdgcn_mfma_f32_32x32x16_bf16((a), (b), (c), 0, 0, 0)

__device__ __forceinline__ bf16x4 cvt4s(float a, float b, float c, float d) {
  bf16x4 r;
  r[0] = (bf16)a; r[1] = (bf16)b; r[2] = (bf16)c; r[3] = (bf16)d;
  return r;
}
__device__ __forceinline__ bf16x8 cvt8(f32x4 a, f32x4 b) {
  bf16x8 r;
  r[0] = (bf16)a[0]; r[1] = (bf16)a[1]; r[2] = (bf16)a[2]; r[3] = (bf16)a[3];
  r[4] = (bf16)b[0]; r[5] = (bf16)b[1]; r[6] = (bf16)b[2]; r[7] = (bf16)b[3];
  return r;
}
__device__ __forceinline__ void gload16(const void* g, void* l) {
  __builtin_amdgcn_global_load_lds((const __attribute__((address_space(1))) void*)g,
                                   (__attribute__((address_space(3))) void*)l, 16, 0, 0);
}

// ---------------------------------------------------------------------------
// fp32 -> bf16 bulk convert; optional scale (mask * log2e).
// ---------------------------------------------------------------------------
__global__ __launch_bounds__(256)
void cvt_k(const float* __restrict__ W, bf16* __restrict__ Wb, float scale)
{
  const size_t i = ((size_t)blockIdx.x * 256 + threadIdx.x) * 8;
  const float* p = W + i;
  f32x4 a = *(const f32x4*)p * scale;
  f32x4 b = *(const f32x4*)(p + 4) * scale;
  *(bf16x8*)(Wb + i) = cvt8(a, b);
}

// ---------------------------------------------------------------------------
// GEMM, m97 structure: C[m][n] = sum_k A[m][k]*B[n][k]; A,B bf16, both staged
// via global_load_lds width-16. MODE selects epilogue:
//   0: scatter Q (linear), K (d-swizzled), VT (n-swizzled) as above.
//   1: + bias -> out fp32 [8192][1024].
// ---------------------------------------------------------------------------
template<int MODE>
__global__ __launch_bounds__(256)
void gemm_bt(const bf16* __restrict__ A, const bf16* __restrict__ B,
             void* __restrict__ O0, bf16* __restrict__ O1, bf16* __restrict__ O2,
             const float* __restrict__ bias)
{
  constexpr int K = 1024;
  __shared__ __attribute__((aligned(16))) bf16 As[128 * 64];
  __shared__ __attribute__((aligned(16))) bf16 Bs[128 * 64];
  const int tid = threadIdx.x, lane = tid & 63, wid = tid >> 6;
  const int m0 = blockIdx.x * 128, n0 = blockIdx.y * 128;
  const int wm = (wid >> 1) * 64, wn = (wid & 1) * 64;
  const int l15 = lane & 15, lg = lane >> 4;

  f32x4 acc[4][4] = {};

  for (int k0 = 0; k0 < K; k0 += 64) {
#pragma unroll
    for (int c = 0; c < 4; ++c) {
      const int seg = wid * 4 + c;
      const int o = seg * 1024 + lane * 16;   // byte offset in 16KB tile
      const int row = o >> 7, colb = o & 127; // 128B per row (64 bf16)
      gload16((const char*)B + (((size_t)(n0 + row) * K + k0) << 1) + colb,
              (char*)Bs + seg * 1024);
      gload16((const char*)A + (((size_t)(m0 + row) * K + k0) << 1) + colb,
              (char*)As + seg * 1024);
    }
    __syncthreads();

    bf16x8 af[4][2], bb[4][2];
#pragma unroll
    for (int i = 0; i < 4; ++i)
#pragma unroll
      for (int kk = 0; kk < 2; ++kk) {
        af[i][kk] = *(const bf16x8*)(As + (wm + i * 16 + l15) * 64 + kk * 32 + lg * 8);
        bb[i][kk] = *(const bf16x8*)(Bs + (wn + i * 16 + l15) * 64 + kk * 32 + lg * 8);
      }
#pragma unroll
    for (int mi = 0; mi < 4; ++mi)
#pragma unroll
      for (int ni = 0; ni < 4; ++ni)
#pragma unroll
        for (int kk = 0; kk < 2; ++kk)
          acc[mi][ni] = MFMA16(af[mi][kk], bb[ni][kk], acc[mi][ni]);
    __syncthreads();
  }

#pragma unroll
  for (int mi = 0; mi < 4; ++mi)
#pragma unroll
    for (int ni = 0; ni < 4; ++ni)
#pragma unroll
      for (int r = 0; r < 4; ++r) {
        const int row = m0 + wm + mi * 16 + lg * 4 + r;
        const int col = n0 + wn + ni * 16 + l15;
        float v = acc[mi][ni][r];
        if (MODE == 0) {
          const int s = col >> 10, h = (col >> 6) & 15, d = col & 63;
          const int b = row >> 11, n = row & 2047;
          const bf16 bv = (bf16)v;
          if (s == 0)
            ((bf16*)O0)[(((size_t)(b * 16 + h) * 2048) + n) * 64 + d] = bv;
          else if (s == 1)   // K, d-swizzled within row
            O1[(((size_t)(b * 16 + h) * 2048) + n) * 64 + (d ^ ((n & 7) << 3))] = bv;
          else               // VT, n-swizzled within 64-tile
            O2[(((size_t)(b * 16 + h) * 64) + d) * 2048 +
               ((n & ~63) | ((n & 63) ^ ((d & 7) << 3)))] = bv;
        } else {
          ((float*)O0)[(size_t)row * 1024 + col] = v + bias[col];
        }
      }
}

// ---------------------------------------------------------------------------
// RoPE in place on Q (linear) and K (d-swizzled). cos/sin fp32 [B][N][32].
// Q additionally pre-scaled by SCALE*log2e so attention softmax is exp2(s).
// For K: stored 8-group g at row n holds logical group g^(n&7); rotation pairs
// live inside groups, so only the cos/sin index changes.
// ---------------------------------------------------------------------------
__global__ __launch_bounds__(256)
void rope_k(bf16* __restrict__ Q, bf16* __restrict__ K,
            const float* __restrict__ C, const float* __restrict__ S)
{
  constexpr float SL = 0.125f * 1.4426950408889634f;
  const int gid = blockIdx.x * 256 + threadIdx.x;
  const int part = gid & 3;
  const int rowid = gid >> 2;
  const int n = rowid & 2047;
  const int b = rowid >> 15;
  const size_t cb0 = ((size_t)(b * 2048 + n)) * 32;

  __attribute__((aligned(16))) bf16 buf[16];

  // ---- Q (linear layout) ----
  {
    float cf[8], sf[8];
    *(f32x4*)cf = *(const f32x4*)(C + cb0 + part * 8);
    *(f32x4*)(cf + 4) = *(const f32x4*)(C + cb0 + part * 8 + 4);
    *(f32x4*)sf = *(const f32x4*)(S + cb0 + part * 8);
    *(f32x4*)(sf + 4) = *(const f32x4*)(S + cb0 + part * 8 + 4);

    bf16* qp = Q + (size_t)rowid * 64 + part * 16;
    *(int4v*)buf = *(const int4v*)qp;
    *(int4v*)(buf + 8) = *(const int4v*)(qp + 8);
#pragma unroll
    for (int j = 0; j < 8; ++j) {
      const float t0 = (float)buf[2 * j], t1 = (float)buf[2 * j + 1];
      buf[2 * j]     = (bf16)((t0 * cf[j] - t1 * sf[j]) * SL);
      buf[2 * j + 1] = (bf16)((t0 * sf[j] + t1 * cf[j]) * SL);
    }
    *(int4v*)qp = *(int4v*)buf;
    *(int4v*)(qp + 8) = *(int4v*)(buf + 8);
  }

  // ---- K (d-swizzled layout) ----
  {
    const int sg = n & 7;
    bf16* kp = K + (size_t)rowid * 64 + part * 16;
    *(int4v*)buf = *(const int4v*)kp;
    *(int4v*)(buf + 8) = *(const int4v*)(kp + 8);
#pragma unroll
    for (int gi = 0; gi < 2; ++gi) {
      const int lg = (2 * part + gi) ^ sg;      // logical 8-group
      const f32x4 c4 = *(const f32x4*)(C + cb0 + lg * 4);
      const f32x4 s4 = *(const f32x4*)(S + cb0 + lg * 4);
#pragma unroll
      for (int m = 0; m < 4; ++m) {
        const float t0 = (float)buf[gi * 8 + 2 * m];
        const float t1 = (float)buf[gi * 8 + 2 * m + 1];
        buf[gi * 8 + 2 * m]     = (bf16)(t0 * c4[m] - t1 * s4[m]);
        buf[gi * 8 + 2 * m + 1] = (bf16)(t0 * s4[m] + t1 * c4[m]);
      }
    }
    *(int4v*)kp = *(int4v*)buf;
    *(int4v*)(kp + 8) = *(int4v*)(buf + 8);
  }
}

// ---------------------------------------------------------------------------
// Flash attention v10: round-10 core (mfma_32x32x16, swapped QK^T, mask as
// MFMA C-init, exp2 softmax, in-register P via cvt_pk+permlane, setprio)
// + 2-PHASE PIPELINE with global_load_lds double-buffer (zero staging VGPRs):
// tile t+1's K/V staged via linear gload_lds (sources pre-swizzled in ws)
// issued at the TOP of tile t; one barrier per tile; the vmcnt drain at the
// barrier now happens AFTER ~1300 cycles of compute cover.
// MM=1: mask bf16*log2e with cur/nxt register rotation; MM=0: fp32 in-tile.
// ---------------------------------------------------------------------------
template<int MM>
__global__ __launch_bounds__(256, 4)
void attn_k(const bf16* __restrict__ Q, const bf16* __restrict__ K,
            const bf16* __restrict__ VT, const void* __restrict__ Mv,
            bf16* __restrict__ O)
{
  constexpr float LOG2E = 1.4426950408889634f;
  constexpr int NT = 32;
  // two K|V buffer sets of 8192 bf16; epilogue overlays [0, 9216)
  __shared__ __attribute__((aligned(16))) bf16 SH[16384];

  const int tid = threadIdx.x, lane = tid & 63, w = tid >> 6;
  const int bh = blockIdx.x;
  const int q0 = blockIdx.y * 128;
  const int b = bh >> 4, h = bh & 15;
  const int l31 = lane & 31, hi = lane >> 5;
  const int swz = (l31 & 7) << 3;

  const bf16* Qb = Q + (size_t)bh * 2048 * 64;
  const bf16* Kb = K + (size_t)bh * 2048 * 64;
  const bf16* Vb = VT + (size_t)bh * 64 * 2048;
  const float* Mqf = (const float*)Mv + (size_t)(q0 + w * 32 + l31) * 2048;
  const bf16*  Mqb = (const bf16*)Mv  + (size_t)(q0 + w * 32 + l31) * 2048;

  bf16x8 qf[4];
  {
    const bf16* qr = Qb + (size_t)(q0 + w * 32 + l31) * 64 + 8 * hi;
#pragma unroll
    for (int j = 0; j < 4; ++j) qf[j] = *(const bf16x8*)(qr + 16 * j);
  }

  f32x16 o[2] = {{0,0,0,0,0,0,0,0,0,0,0,0,0,0,0,0},
                 {0,0,0,0,0,0,0,0,0,0,0,0,0,0,0,0}};
  float li = 0.f;

  // staging: 512 16B-slots; slot idx -> K row idx>>3, group idx&7 (linear,
  // sources pre-swizzled). Per it in {0,1}: wave-uniform LDS base.
#define STAGE_TILE(KVN, BUFSEL) do {                                          \
    bf16* Ktn = SH + (BUFSEL) * 8192;                                         \
    bf16* Vtn = Ktn + 4096;                                                   \
    _Pragma("unroll")                                                         \
    for (int it = 0; it < 2; ++it) {                                          \
      const int idx = it * 256 + tid;                                         \
      gload16((const char*)Kb + (((size_t)(KVN) * 64 + idx * 8) << 1),        \
              (char*)Ktn + it * 4096 + w * 1024);                             \
      gload16((const char*)Vb +                                               \
                  (((size_t)(idx >> 3) * 2048 + (KVN) + (idx & 7) * 8) << 1), \
              (char*)Vtn + it * 4096 + w * 1024);                             \
    }                                                                         \
  } while (0)

  bf16x4 mkb_cur[2][4], mkb_nxt[2][4];

  // ---- prologue: stage tile 0, prefetch mask(0) ----
  STAGE_TILE(0, 0);
  if (MM == 1) {
#pragma unroll
    for (int sub = 0; sub < 2; ++sub)
#pragma unroll
      for (int rg = 0; rg < 4; ++rg)
        mkb_cur[sub][rg] = *(const bf16x4*)(Mqb + 32 * sub + 8 * rg + 4 * hi);
  }
  __syncthreads();

  for (int t = 0; t < NT; ++t) {
    bf16* Kt = SH + (t & 1) * 8192;
    bf16* Vt = Kt + 4096;

    // issue next tile's staging + mask loads (land under this tile's compute)
    if (t + 1 < NT) {
      const int kvn = (t + 1) * 64;
      STAGE_TILE(kvn, (t + 1) & 1);
      if (MM == 1) {
#pragma unroll
        for (int sub = 0; sub < 2; ++sub)
#pragma unroll
          for (int rg = 0; rg < 4; ++rg)
            mkb_nxt[sub][rg] = *(const bf16x4*)(Mqb + kvn + 32 * sub + 8 * rg + 4 * hi);
      }
    }
    f32x4 mkf[2][4];
    if (MM == 0) {
      const int kv0 = t * 64;
#pragma unroll
      for (int sub = 0; sub < 2; ++sub)
#pragma unroll
        for (int rg = 0; rg < 4; ++rg)
          mkf[sub][rg] = *(const f32x4*)(Mqf + kv0 + 32 * sub + 8 * rg + 4 * hi);
    }

#pragma unroll
    for (int sub = 0; sub < 2; ++sub) {
      // S^T = K Q'^T with C initialized to mask*log2e (Q' pre-scaled)
      f32x16 s;
#pragma unroll
      for (int rg = 0; rg < 4; ++rg)
#pragma unroll
        for (int i = 0; i < 4; ++i)
          s[4 * rg + i] = (MM == 0) ? mkf[sub][rg][i] * LOG2E
                                    : (float)mkb_cur[sub][rg][i];
      __builtin_amdgcn_s_setprio(1);
#pragma unroll
      for (int j = 0; j < 4; ++j) {
        const bf16x8 kf = *(const bf16x8*)(
            Kt + (sub * 32 + l31) * 64 + ((16 * j + 8 * hi) ^ swz));
        s = MFMA32(kf, qf[j], s);
      }
      __builtin_amdgcn_s_setprio(0);

      // softmax: p = exp2(s); row-sum 16 local + 1 shfl
      float rs = 0.f;
#pragma unroll
      for (int e = 0; e < 16; ++e) {
        const float p = __builtin_exp2f(s[e]);
        s[e] = p;
        rs += p;
      }
      rs += __shfl_xor(rs, 32);
      li += rs;

      // T12: P -> bf16 in-register; permlane32_swap builds PV B-fragments
      uint32_t pk0, pk1, pk2, pk3, pk4, pk5, pk6, pk7;
      asm("v_cvt_pk_bf16_f32 %0, %1, %2" : "=v"(pk0) : "v"(s[0]),  "v"(s[1]));
      asm("v_cvt_pk_bf16_f32 %0, %1, %2" : "=v"(pk1) : "v"(s[2]),  "v"(s[3]));
      asm("v_cvt_pk_bf16_f32 %0, %1, %2" : "=v"(pk2) : "v"(s[4]),  "v"(s[5]));
      asm("v_cvt_pk_bf16_f32 %0, %1, %2" : "=v"(pk3) : "v"(s[6]),  "v"(s[7]));
      asm("v_cvt_pk_bf16_f32 %0, %1, %2" : "=v"(pk4) : "v"(s[8]),  "v"(s[9]));
      asm("v_cvt_pk_bf16_f32 %0, %1, %2" : "=v"(pk5) : "v"(s[10]), "v"(s[11]));
      asm("v_cvt_pk_bf16_f32 %0, %1, %2" : "=v"(pk6) : "v"(s[12]), "v"(s[13]));
      asm("v_cvt_pk_bf16_f32 %0, %1, %2" : "=v"(pk7) : "v"(s[14]), "v"(s[15]));
      asm("v_permlane32_swap_b32 %0, %1" : "+v"(pk0), "+v"(pk2));
      asm("v_permlane32_swap_b32 %0, %1" : "+v"(pk1), "+v"(pk3));
      asm("v_permlane32_swap_b32 %0, %1" : "+v"(pk4), "+v"(pk6));
      asm("v_permlane32_swap_b32 %0, %1" : "+v"(pk5), "+v"(pk7));
      uint32_t pau[2][4] = {{pk0, pk1, pk2, pk3}, {pk4, pk5, pk6, pk7}};
      bf16x8 pa[2];
      __builtin_memcpy(&pa[0], pau[0], 16);
      __builtin_memcpy(&pa[1], pau[1], 16);

      // PV: O^T[d'][q] += V^T[d'][kv] P^T[kv][q]
      __builtin_amdgcn_s_setprio(1);
#pragma unroll
      for (int kh = 0; kh < 2; ++kh)
#pragma unroll
        for (int dblk = 0; dblk < 2; ++dblk) {
          const bf16x8 vf = *(const bf16x8*)(
              Vt + (dblk * 32 + l31) * 64 + ((sub * 32 + kh * 16 + 8 * hi) ^ swz));
          o[dblk] = MFMA32(vf, pa[kh], o[dblk]);
        }
      __builtin_amdgcn_s_setprio(0);
    }

    if (MM == 1 && t + 1 < NT) {
#pragma unroll
      for (int sub = 0; sub < 2; ++sub)
#pragma unroll
        for (int rg = 0; rg < 4; ++rg)
          mkb_cur[sub][rg] = mkb_nxt[sub][rg];
    }
    __syncthreads();
  }
#undef STAGE_TILE

  // epilogue: normalize (lane-local), transpose via LDS, b128 stores.
  const float inv = 1.f / li;
  bf16* ow = SH + w * 2304;
#pragma unroll
  for (int dblk = 0; dblk < 2; ++dblk)
#pragma unroll
    for (int rg = 0; rg < 4; ++rg)
      *(bf16x4*)(ow + l31 * 72 + dblk * 32 + 8 * rg + 4 * hi) =
          cvt4s(o[dblk][4 * rg] * inv, o[dblk][4 * rg + 1] * inv,
                o[dblk][4 * rg + 2] * inv, o[dblk][4 * rg + 3] * inv);
  asm volatile("s_waitcnt lgkmcnt(0)" ::: "memory");
  __builtin_amdgcn_sched_barrier(0);
#pragma unroll
  for (int p = 0; p < 4; ++p) {
    const int row = p * 8 + (lane >> 3);
    const int n = q0 + w * 32 + row;
    const int4v v = *(const int4v*)(ow + row * 72 + (lane & 7) * 8);
    *(int4v*)(O + ((size_t)b * 2048 + n) * 1024 + h * 64 + (lane & 7) * 8) = v;
  }
}

// ---------------------------------------------------------------------------
extern "C" void kernel_launch(void* const* d_in, const int* in_sizes, int n_in,
                              void* d_out, int out_size, void* d_ws, size_t ws_size,
                              hipStream_t stream)
{
  (void)in_sizes; (void)n_in; (void)out_size;
  const float* x     = (const float*)d_in[0];
  const float* fcos  = (const float*)d_in[1];
  const float* fsin  = (const float*)d_in[2];
  const float* mask  = (const float*)d_in[3];
  const float* wqkv  = (const float*)d_in[4];
  const float* wproj = (const float*)d_in[5];
  const float* bproj = (const float*)d_in[6];
  float* out = (float*)d_out;

  const size_t SZ  = (size_t)64 * 2048 * 64 * 2;           // 16.78 MB
  const size_t WQB = (size_t)3072 * 1024 * 2;              // 6.29 MB
  const size_t WPB = (size_t)1024 * 1024 * 2;              // 2.10 MB
  const size_t MKB = (size_t)2048 * 2048 * 2;              // 8.39 MB (bf16 mask)
  const size_t BASE = 4 * SZ + WQB + WPB;                  // 75.5 MB (proven)
  if (ws_size < BASE) return;                              // fail loudly
  char* ws = (char*)d_ws;
  bf16* Qr  = (bf16*)(ws);
  bf16* Kr  = (bf16*)(ws + SZ);
  bf16* VT  = (bf16*)(ws + 2 * SZ);
  bf16* Ob  = (bf16*)(ws + 3 * SZ);   // doubles as bf16(x) before attn runs
  bf16* Wqb = (bf16*)(ws + 4 * SZ);
  bf16* Wpb = (bf16*)(ws + 4 * SZ + WQB);
  bf16* Mb  = (bf16*)(ws + BASE);
  const bool useMb = (ws_size >= BASE + MKB);
  constexpr float LOG2E = 1.4426950408889634f;
  bf16* Xb = Ob;  // x-bf16 lives in the Ob slot (dead until attn)

  cvt_k<<<4096, 256, 0, stream>>>(x, Xb, 1.0f);
  cvt_k<<<1536, 256, 0, stream>>>(wqkv, Wqb, 1.0f);
  cvt_k<<<512, 256, 0, stream>>>(wproj, Wpb, 1.0f);
  if (useMb) cvt_k<<<2048, 256, 0, stream>>>(mask, Mb, LOG2E);
  gemm_bt<0><<<dim3(64, 24), 256, 0, stream>>>(Xb, Wqb, Qr, Kr, VT, nullptr);
  rope_k<<<2048, 256, 0, stream>>>(Qr, Kr, fcos, fsin);
  if (useMb)
    attn_k<1><<<dim3(64, 16), 256, 0, stream>>>(Qr, Kr, VT, Mb, Ob);
  else
    attn_k<0><<<dim3(64, 16), 256, 0, stream>>>(Qr, Kr, VT, mask, Ob);
  gemm_bt<1><<<dim3(64, 8), 256, 0, stream>>>(Ob, Wpb, out, nullptr, nullptr, bproj);
}

// Round 13
// 292.051 us; speedup vs baseline: 1.1498x; 1.0133x over previous
//
#include <hip/hip_runtime.h>
#include <hip/hip_bf16.h>
#include <stdint.h>

// Problem: B=4, N=2048, C=1024, H=16, D=64.
// Device dtypes: ALL inputs fp32, output fp32. Internal: bf16 MFMA, fp32 accum.
// x @ Wqkv.T -> RoPE(q,k) -> per-(b,h) softmax(q k^T /8 + mask) v -> @ Wproj.T + b
//
// K in ws is stored D-SWIZZLED:  ws_K[n][x]  = K[n][x ^ ((n&7)<<3)]
// VT in ws is stored N-SWIZZLED: ws_VT[d][m] = VT[d][(m&~63) | ((m&63)^((d&7)<<3))]
// so attn can stage via linear global_load_lds and read with the XOR swizzle.

typedef __bf16 bf16;
typedef __bf16 bf16x4 __attribute__((ext_vector_type(4)));
typedef __bf16 bf16x8 __attribute__((ext_vector_type(8)));
typedef float  f32x4  __attribute__((ext_vector_type(4)));
typedef float  f32x16 __attribute__((ext_vector_type(16)));
typedef int    int4v  __attribute__((ext_vector_type(4)));

#define MFMA16(a, b, c) __builtin_amdgcn_mfma_f32_16x16x32_bf16((a), (b), (c), 0, 0, 0)
#define MFMA32(a, b, c) __builtin_amdgcn_mfma_f32_32x32x16_bf16((a), (b), (c), 0, 0, 0)

__device__ __forceinline__ bf16x4 cvt4s(float a, float b, float c, float d) {
  bf16x4 r;
  r[0] = (bf16)a; r[1] = (bf16)b; r[2] = (bf16)c; r[3] = (bf16)d;
  return r;
}
__device__ __forceinline__ bf16x8 cvt8(f32x4 a, f32x4 b) {
  bf16x8 r;
  r[0] = (bf16)a[0]; r[1] = (bf16)a[1]; r[2] = (bf16)a[2]; r[3] = (bf16)a[3];
  r[4] = (bf16)b[0]; r[5] = (bf16)b[1]; r[6] = (bf16)b[2]; r[7] = (bf16)b[3];
  return r;
}
__device__ __forceinline__ void gload16(const void* g, void* l) {
  __builtin_amdgcn_global_load_lds((const __attribute__((address_space(1))) void*)g,
                                   (__attribute__((address_space(3))) void*)l, 16, 0, 0);
}

// ---------------------------------------------------------------------------
// fp32 -> bf16 bulk convert; optional scale (mask * log2e).
// ---------------------------------------------------------------------------
__global__ __launch_bounds__(256)
void cvt_k(const float* __restrict__ W, bf16* __restrict__ Wb, float scale)
{
  const size_t i = ((size_t)blockIdx.x * 256 + threadIdx.x) * 8;
  const float* p = W + i;
  f32x4 a = *(const f32x4*)p * scale;
  f32x4 b = *(const f32x4*)(p + 4) * scale;
  *(bf16x8*)(Wb + i) = cvt8(a, b);
}

// ---------------------------------------------------------------------------
// GEMM, m97 structure: C[m][n] = sum_k A[m][k]*B[n][k]; A,B bf16, both staged
// via global_load_lds width-16.
// MODE 0: scatter Q (linear), K (d-swizzled), VT (n-swizzled). Each block's
//         128 cols lie in exactly one of {Q,K,V} (128|1024) -> specialized
//         LDS-retile epilogue with b128 coalesced stores (was 64x 2B scatter).
// MODE 1: + bias -> out fp32 [8192][1024] (direct, already coalesced).
// ---------------------------------------------------------------------------
template<int MODE>
__global__ __launch_bounds__(256)
void gemm_bt(const bf16* __restrict__ A, const bf16* __restrict__ B,
             void* __restrict__ O0, bf16* __restrict__ O1, bf16* __restrict__ O2,
             const float* __restrict__ bias)
{
  constexpr int K = 1024;
  // MODE 0: union { As[8192] | Bs[8192] } with epilogue tile T[128][136]
  __shared__ __attribute__((aligned(16))) bf16 S[MODE == 0 ? 17408 : 16384];
  bf16* As = S;
  bf16* Bs = S + 128 * 64;
  const int tid = threadIdx.x, lane = tid & 63, wid = tid >> 6;
  const int m0 = blockIdx.x * 128, n0 = blockIdx.y * 128;
  const int wm = (wid >> 1) * 64, wn = (wid & 1) * 64;
  const int l15 = lane & 15, lg = lane >> 4;

  f32x4 acc[4][4] = {};

  for (int k0 = 0; k0 < K; k0 += 64) {
#pragma unroll
    for (int c = 0; c < 4; ++c) {
      const int seg = wid * 4 + c;
      const int o = seg * 1024 + lane * 16;   // byte offset in 16KB tile
      const int row = o >> 7, colb = o & 127; // 128B per row (64 bf16)
      gload16((const char*)B + (((size_t)(n0 + row) * K + k0) << 1) + colb,
              (char*)Bs + seg * 1024);
      gload16((const char*)A + (((size_t)(m0 + row) * K + k0) << 1) + colb,
              (char*)As + seg * 1024);
    }
    __syncthreads();

    bf16x8 af[4][2], bb[4][2];
#pragma unroll
    for (int i = 0; i < 4; ++i)
#pragma unroll
      for (int kk = 0; kk < 2; ++kk) {
        af[i][kk] = *(const bf16x8*)(As + (wm + i * 16 + l15) * 64 + kk * 32 + lg * 8);
        bb[i][kk] = *(const bf16x8*)(Bs + (wn + i * 16 + l15) * 64 + kk * 32 + lg * 8);
      }
#pragma unroll
    for (int mi = 0; mi < 4; ++mi)
#pragma unroll
      for (int ni = 0; ni < 4; ++ni)
#pragma unroll
        for (int kk = 0; kk < 2; ++kk)
          acc[mi][ni] = MFMA16(af[mi][kk], bb[ni][kk], acc[mi][ni]);
    __syncthreads();
  }

  if (MODE == 0) {
    // ---- LDS re-tile epilogue: acc -> T[n_local][c] (bf16, stride 136) ----
    bf16* T = S;
#pragma unroll
    for (int mi = 0; mi < 4; ++mi)
#pragma unroll
      for (int ni = 0; ni < 4; ++ni)
#pragma unroll
        for (int r = 0; r < 4; ++r)
          T[(wm + mi * 16 + lg * 4 + r) * 136 + wn + ni * 16 + l15] =
              (bf16)acc[mi][ni][r];
    __syncthreads();

    const int s = n0 >> 10;            // 0:Q 1:K 2:V (uniform per block)
    const int h0 = (n0 >> 6) & 15;
    if (s < 2) {
      // Q/K: rows of T are [n][d] -> b128 reads + b128 stores
      bf16* dst = (s == 0) ? (bf16*)O0 : O1;
      const int nl = tid >> 1, ch = (tid & 1) * 64;
      const int row = m0 + nl, b = row >> 11, n = row & 2047;
#pragma unroll
      for (int j = 0; j < 8; ++j) {
        const int c = ch + j * 8;
        const int h = h0 + (c >> 6), d0 = c & 63;
        const int ds = (s == 1) ? (d0 ^ ((n & 7) << 3)) : d0;
        *(int4v*)(dst + (((size_t)(b * 16 + h) * 2048) + n) * 64 + ds) =
            *(const int4v*)(T + nl * 136 + c);
      }
    } else {
      // V: gather 8-elem columns of T -> b128 stores along (pre-swizzled) n
      const int c = tid >> 1, nh = (tid & 1) * 64;
      const int h = h0 + (c >> 6), d = c & 63;
      const int b = m0 >> 11, nb = m0 & 2047;
#pragma unroll
      for (int j = 0; j < 8; ++j) {
        const int n8 = nh + j * 8;
        __attribute__((aligned(16))) bf16 tmp[8];
#pragma unroll
        for (int i = 0; i < 8; ++i) tmp[i] = T[(n8 + i) * 136 + c];
        const int ng = nb + n8;
        const int nswz = (ng & ~63) | ((ng & 63) ^ ((d & 7) << 3));
        *(int4v*)(O2 + ((size_t)(b * 16 + h) * 64 + d) * 2048 + nswz) =
            *(const int4v*)tmp;
      }
    }
  } else {
#pragma unroll
    for (int mi = 0; mi < 4; ++mi)
#pragma unroll
      for (int ni = 0; ni < 4; ++ni)
#pragma unroll
        for (int r = 0; r < 4; ++r) {
          const int row = m0 + wm + mi * 16 + lg * 4 + r;
          const int col = n0 + wn + ni * 16 + l15;
          ((float*)O0)[(size_t)row * 1024 + col] = acc[mi][ni][r] + bias[col];
        }
  }
}

// ---------------------------------------------------------------------------
// RoPE in place on Q (linear) and K (d-swizzled). cos/sin fp32 [B][N][32].
// Q additionally pre-scaled by SCALE*log2e so attention softmax is exp2(s).
// For K: stored 8-group g at row n holds logical group g^(n&7).
// ---------------------------------------------------------------------------
__global__ __launch_bounds__(256)
void rope_k(bf16* __restrict__ Q, bf16* __restrict__ K,
            const float* __restrict__ C, const float* __restrict__ S)
{
  constexpr float SL = 0.125f * 1.4426950408889634f;
  const int gid = blockIdx.x * 256 + threadIdx.x;
  const int part = gid & 3;
  const int rowid = gid >> 2;
  const int n = rowid & 2047;
  const int b = rowid >> 15;
  const size_t cb0 = ((size_t)(b * 2048 + n)) * 32;

  __attribute__((aligned(16))) bf16 buf[16];

  // ---- Q (linear layout) ----
  {
    float cf[8], sf[8];
    *(f32x4*)cf = *(const f32x4*)(C + cb0 + part * 8);
    *(f32x4*)(cf + 4) = *(const f32x4*)(C + cb0 + part * 8 + 4);
    *(f32x4*)sf = *(const f32x4*)(S + cb0 + part * 8);
    *(f32x4*)(sf + 4) = *(const f32x4*)(S + cb0 + part * 8 + 4);

    bf16* qp = Q + (size_t)rowid * 64 + part * 16;
    *(int4v*)buf = *(const int4v*)qp;
    *(int4v*)(buf + 8) = *(const int4v*)(qp + 8);
#pragma unroll
    for (int j = 0; j < 8; ++j) {
      const float t0 = (float)buf[2 * j], t1 = (float)buf[2 * j + 1];
      buf[2 * j]     = (bf16)((t0 * cf[j] - t1 * sf[j]) * SL);
      buf[2 * j + 1] = (bf16)((t0 * sf[j] + t1 * cf[j]) * SL);
    }
    *(int4v*)qp = *(int4v*)buf;
    *(int4v*)(qp + 8) = *(int4v*)(buf + 8);
  }

  // ---- K (d-swizzled layout) ----
  {
    const int sg = n & 7;
    bf16* kp = K + (size_t)rowid * 64 + part * 16;
    *(int4v*)buf = *(const int4v*)kp;
    *(int4v*)(buf + 8) = *(const int4v*)(kp + 8);
#pragma unroll
    for (int gi = 0; gi < 2; ++gi) {
      const int lg = (2 * part + gi) ^ sg;      // logical 8-group
      const f32x4 c4 = *(const f32x4*)(C + cb0 + lg * 4);
      const f32x4 s4 = *(const f32x4*)(S + cb0 + lg * 4);
#pragma unroll
      for (int m = 0; m < 4; ++m) {
        const float t0 = (float)buf[gi * 8 + 2 * m];
        const float t1 = (float)buf[gi * 8 + 2 * m + 1];
        buf[gi * 8 + 2 * m]     = (bf16)(t0 * c4[m] - t1 * s4[m]);
        buf[gi * 8 + 2 * m + 1] = (bf16)(t0 * s4[m] + t1 * c4[m]);
      }
    }
    *(int4v*)kp = *(int4v*)buf;
    *(int4v*)(kp + 8) = *(int4v*)(buf + 8);
  }
}

// ---------------------------------------------------------------------------
// Flash attention (round-12, unchanged): mfma_32x32x16, swapped QK^T, mask as
// MFMA C-init, exp2 softmax, in-register P via cvt_pk+permlane, setprio,
// 2-phase gload_lds double-buffer with pre-swizzled ws sources.
// MM=1: mask bf16*log2e with cur/nxt register rotation; MM=0: fp32 in-tile.
// ---------------------------------------------------------------------------
template<int MM>
__global__ __launch_bounds__(256, 4)
void attn_k(const bf16* __restrict__ Q, const bf16* __restrict__ K,
            const bf16* __restrict__ VT, const void* __restrict__ Mv,
            bf16* __restrict__ O)
{
  constexpr float LOG2E = 1.4426950408889634f;
  constexpr int NT = 32;
  __shared__ __attribute__((aligned(16))) bf16 SH[16384];

  const int tid = threadIdx.x, lane = tid & 63, w = tid >> 6;
  const int bh = blockIdx.x;
  const int q0 = blockIdx.y * 128;
  const int b = bh >> 4, h = bh & 15;
  const int l31 = lane & 31, hi = lane >> 5;
  const int swz = (l31 & 7) << 3;

  const bf16* Qb = Q + (size_t)bh * 2048 * 64;
  const bf16* Kb = K + (size_t)bh * 2048 * 64;
  const bf16* Vb = VT + (size_t)bh * 64 * 2048;
  const float* Mqf = (const float*)Mv + (size_t)(q0 + w * 32 + l31) * 2048;
  const bf16*  Mqb = (const bf16*)Mv  + (size_t)(q0 + w * 32 + l31) * 2048;

  bf16x8 qf[4];
  {
    const bf16* qr = Qb + (size_t)(q0 + w * 32 + l31) * 64 + 8 * hi;
#pragma unroll
    for (int j = 0; j < 4; ++j) qf[j] = *(const bf16x8*)(qr + 16 * j);
  }

  f32x16 o[2] = {{0,0,0,0,0,0,0,0,0,0,0,0,0,0,0,0},
                 {0,0,0,0,0,0,0,0,0,0,0,0,0,0,0,0}};
  float li = 0.f;

#define STAGE_TILE(KVN, BUFSEL) do {                                          \
    bf16* Ktn = SH + (BUFSEL) * 8192;                                         \
    bf16* Vtn = Ktn + 4096;                                                   \
    _Pragma("unroll")                                                         \
    for (int it = 0; it < 2; ++it) {                                          \
      const int idx = it * 256 + tid;                                         \
      gload16((const char*)Kb + (((size_t)(KVN) * 64 + idx * 8) << 1),        \
              (char*)Ktn + it * 4096 + w * 1024);                             \
      gload16((const char*)Vb +                                               \
                  (((size_t)(idx >> 3) * 2048 + (KVN) + (idx & 7) * 8) << 1), \
              (char*)Vtn + it * 4096 + w * 1024);                             \
    }                                                                         \
  } while (0)

  bf16x4 mkb_cur[2][4], mkb_nxt[2][4];

  STAGE_TILE(0, 0);
  if (MM == 1) {
#pragma unroll
    for (int sub = 0; sub < 2; ++sub)
#pragma unroll
      for (int rg = 0; rg < 4; ++rg)
        mkb_cur[sub][rg] = *(const bf16x4*)(Mqb + 32 * sub + 8 * rg + 4 * hi);
  }
  __syncthreads();

  for (int t = 0; t < NT; ++t) {
    bf16* Kt = SH + (t & 1) * 8192;
    bf16* Vt = Kt + 4096;

    if (t + 1 < NT) {
      const int kvn = (t + 1) * 64;
      STAGE_TILE(kvn, (t + 1) & 1);
      if (MM == 1) {
#pragma unroll
        for (int sub = 0; sub < 2; ++sub)
#pragma unroll
          for (int rg = 0; rg < 4; ++rg)
            mkb_nxt[sub][rg] = *(const bf16x4*)(Mqb + kvn + 32 * sub + 8 * rg + 4 * hi);
      }
    }
    f32x4 mkf[2][4];
    if (MM == 0) {
      const int kv0 = t * 64;
#pragma unroll
      for (int sub = 0; sub < 2; ++sub)
#pragma unroll
        for (int rg = 0; rg < 4; ++rg)
          mkf[sub][rg] = *(const f32x4*)(Mqf + kv0 + 32 * sub + 8 * rg + 4 * hi);
    }

#pragma unroll
    for (int sub = 0; sub < 2; ++sub) {
      f32x16 s;
#pragma unroll
      for (int rg = 0; rg < 4; ++rg)
#pragma unroll
        for (int i = 0; i < 4; ++i)
          s[4 * rg + i] = (MM == 0) ? mkf[sub][rg][i] * LOG2E
                                    : (float)mkb_cur[sub][rg][i];
      __builtin_amdgcn_s_setprio(1);
#pragma unroll
      for (int j = 0; j < 4; ++j) {
        const bf16x8 kf = *(const bf16x8*)(
            Kt + (sub * 32 + l31) * 64 + ((16 * j + 8 * hi) ^ swz));
        s = MFMA32(kf, qf[j], s);
      }
      __builtin_amdgcn_s_setprio(0);

      float rs = 0.f;
#pragma unroll
      for (int e = 0; e < 16; ++e) {
        const float p = __builtin_exp2f(s[e]);
        s[e] = p;
        rs += p;
      }
      rs += __shfl_xor(rs, 32);
      li += rs;

      uint32_t pk0, pk1, pk2, pk3, pk4, pk5, pk6, pk7;
      asm("v_cvt_pk_bf16_f32 %0, %1, %2" : "=v"(pk0) : "v"(s[0]),  "v"(s[1]));
      asm("v_cvt_pk_bf16_f32 %0, %1, %2" : "=v"(pk1) : "v"(s[2]),  "v"(s[3]));
      asm("v_cvt_pk_bf16_f32 %0, %1, %2" : "=v"(pk2) : "v"(s[4]),  "v"(s[5]));
      asm("v_cvt_pk_bf16_f32 %0, %1, %2" : "=v"(pk3) : "v"(s[6]),  "v"(s[7]));
      asm("v_cvt_pk_bf16_f32 %0, %1, %2" : "=v"(pk4) : "v"(s[8]),  "v"(s[9]));
      asm("v_cvt_pk_bf16_f32 %0, %1, %2" : "=v"(pk5) : "v"(s[10]), "v"(s[11]));
      asm("v_cvt_pk_bf16_f32 %0, %1, %2" : "=v"(pk6) : "v"(s[12]), "v"(s[13]));
      asm("v_cvt_pk_bf16_f32 %0, %1, %2" : "=v"(pk7) : "v"(s[14]), "v"(s[15]));
      asm("v_permlane32_swap_b32 %0, %1" : "+v"(pk0), "+v"(pk2));
      asm("v_permlane32_swap_b32 %0, %1" : "+v"(pk1), "+v"(pk3));
      asm("v_permlane32_swap_b32 %0, %1" : "+v"(pk4), "+v"(pk6));
      asm("v_permlane32_swap_b32 %0, %1" : "+v"(pk5), "+v"(pk7));
      uint32_t pau[2][4] = {{pk0, pk1, pk2, pk3}, {pk4, pk5, pk6, pk7}};
      bf16x8 pa[2];
      __builtin_memcpy(&pa[0], pau[0], 16);
      __builtin_memcpy(&pa[1], pau[1], 16);

      __builtin_amdgcn_s_setprio(1);
#pragma unroll
      for (int kh = 0; kh < 2; ++kh)
#pragma unroll
        for (int dblk = 0; dblk < 2; ++dblk) {
          const bf16x8 vf = *(const bf16x8*)(
              Vt + (dblk * 32 + l31) * 64 + ((sub * 32 + kh * 16 + 8 * hi) ^ swz));
          o[dblk] = MFMA32(vf, pa[kh], o[dblk]);
        }
      __builtin_amdgcn_s_setprio(0);
    }

    if (MM == 1 && t + 1 < NT) {
#pragma unroll
      for (int sub = 0; sub < 2; ++sub)
#pragma unroll
        for (int rg = 0; rg < 4; ++rg)
          mkb_cur[sub][rg] = mkb_nxt[sub][rg];
    }
    __syncthreads();
  }
#undef STAGE_TILE

  const float inv = 1.f / li;
  bf16* ow = SH + w * 2304;
#pragma unroll
  for (int dblk = 0; dblk < 2; ++dblk)
#pragma unroll
    for (int rg = 0; rg < 4; ++rg)
      *(bf16x4*)(ow + l31 * 72 + dblk * 32 + 8 * rg + 4 * hi) =
          cvt4s(o[dblk][4 * rg] * inv, o[dblk][4 * rg + 1] * inv,
                o[dblk][4 * rg + 2] * inv, o[dblk][4 * rg + 3] * inv);
  asm volatile("s_waitcnt lgkmcnt(0)" ::: "memory");
  __builtin_amdgcn_sched_barrier(0);
#pragma unroll
  for (int p = 0; p < 4; ++p) {
    const int row = p * 8 + (lane >> 3);
    const int n = q0 + w * 32 + row;
    const int4v v = *(const int4v*)(ow + row * 72 + (lane & 7) * 8);
    *(int4v*)(O + ((size_t)b * 2048 + n) * 1024 + h * 64 + (lane & 7) * 8) = v;
  }
}

// ---------------------------------------------------------------------------
extern "C" void kernel_launch(void* const* d_in, const int* in_sizes, int n_in,
                              void* d_out, int out_size, void* d_ws, size_t ws_size,
                              hipStream_t stream)
{
  (void)in_sizes; (void)n_in; (void)out_size;
  const float* x     = (const float*)d_in[0];
  const float* fcos  = (const float*)d_in[1];
  const float* fsin  = (const float*)d_in[2];
  const float* mask  = (const float*)d_in[3];
  const float* wqkv  = (const float*)d_in[4];
  const float* wproj = (const float*)d_in[5];
  const float* bproj = (const float*)d_in[6];
  float* out = (float*)d_out;

  const size_t SZ  = (size_t)64 * 2048 * 64 * 2;           // 16.78 MB
  const size_t WQB = (size_t)3072 * 1024 * 2;              // 6.29 MB
  const size_t WPB = (size_t)1024 * 1024 * 2;              // 2.10 MB
  const size_t MKB = (size_t)2048 * 2048 * 2;              // 8.39 MB (bf16 mask)
  const size_t BASE = 4 * SZ + WQB + WPB;                  // 75.5 MB (proven)
  if (ws_size < BASE) return;                              // fail loudly
  char* ws = (char*)d_ws;
  bf16* Qr  = (bf16*)(ws);
  bf16* Kr  = (bf16*)(ws + SZ);
  bf16* VT  = (bf16*)(ws + 2 * SZ);
  bf16* Ob  = (bf16*)(ws + 3 * SZ);   // doubles as bf16(x) before attn runs
  bf16* Wqb = (bf16*)(ws + 4 * SZ);
  bf16* Wpb = (bf16*)(ws + 4 * SZ + WQB);
  bf16* Mb  = (bf16*)(ws + BASE);
  const bool useMb = (ws_size >= BASE + MKB);
  constexpr float LOG2E = 1.4426950408889634f;
  bf16* Xb = Ob;  // x-bf16 lives in the Ob slot (dead until attn)

  cvt_k<<<4096, 256, 0, stream>>>(x, Xb, 1.0f);
  cvt_k<<<1536, 256, 0, stream>>>(wqkv, Wqb, 1.0f);
  cvt_k<<<512, 256, 0, stream>>>(wproj, Wpb, 1.0f);
  if (useMb) cvt_k<<<2048, 256, 0, stream>>>(mask, Mb, LOG2E);
  gemm_bt<0><<<dim3(64, 24), 256, 0, stream>>>(Xb, Wqb, Qr, Kr, VT, nullptr);
  rope_k<<<2048, 256, 0, stream>>>(Qr, Kr, fcos, fsin);
  if (useMb)
    attn_k<1><<<dim3(64, 16), 256, 0, stream>>>(Qr, Kr, VT, Mb, Ob);
  else
    attn_k<0><<<dim3(64, 16), 256, 0, stream>>>(Qr, Kr, VT, mask, Ob);
  gemm_bt<1><<<dim3(64, 8), 256, 0, stream>>>(Ob, Wpb, out, nullptr, nullptr, bproj);
}

// Round 15
// 277.770 us; speedup vs baseline: 1.2090x; 1.0514x over previous
//
#include <hip/hip_runtime.h>
#include <hip/hip_bf16.h>
#include <stdint.h>

// Problem: B=4, N=2048, C=1024, H=16, D=64.
// Device dtypes: ALL inputs fp32, output fp32. Internal: bf16 MFMA, fp32 accum.
// x @ Wqkv.T -> RoPE(q,k) -> per-(b,h) softmax(q k^T /8 + mask) v -> @ Wproj.T + b
//
// K in ws is stored D-SWIZZLED:  ws_K[n][x]  = K[n][x ^ ((n&7)<<3)]
// VT in ws is stored N-SWIZZLED: ws_VT[d][m] = VT[d][(m&~63) | ((m&63)^((d&7)<<3))]
// so attn can stage via linear global_load_lds and read with the XOR swizzle.
// RoPE is a separate kernel (bit-identical to the round-13 passing chain).

typedef __bf16 bf16;
typedef __bf16 bf16x4 __attribute__((ext_vector_type(4)));
typedef __bf16 bf16x8 __attribute__((ext_vector_type(8)));
typedef float  f32x4  __attribute__((ext_vector_type(4)));
typedef float  f32x16 __attribute__((ext_vector_type(16)));
typedef int    int4v  __attribute__((ext_vector_type(4)));

#define MFMA16(a, b, c) __builtin_amdgcn_mfma_f32_16x16x32_bf16((a), (b), (c), 0, 0, 0)
#define MFMA32(a, b, c) __builtin_amdgcn_mfma_f32_32x32x16_bf16((a), (b), (c), 0, 0, 0)

__device__ __forceinline__ bf16x4 cvt4s(float a, float b, float c, float d) {
  bf16x4 r;
  r[0] = (bf16)a; r[1] = (bf16)b; r[2] = (bf16)c; r[3] = (bf16)d;
  return r;
}
__device__ __forceinline__ bf16x8 cvt8(f32x4 a, f32x4 b) {
  bf16x8 r;
  r[0] = (bf16)a[0]; r[1] = (bf16)a[1]; r[2] = (bf16)a[2]; r[3] = (bf16)a[3];
  r[4] = (bf16)b[0]; r[5] = (bf16)b[1]; r[6] = (bf16)b[2]; r[7] = (bf16)b[3];
  return r;
}
__device__ __forceinline__ void gload16(const void* g, void* l) {
  __builtin_amdgcn_global_load_lds((const __attribute__((address_space(1))) void*)g,
                                   (__attribute__((address_space(3))) void*)l, 16, 0, 0);
}

// ---------------------------------------------------------------------------
// Fused fp32->bf16 bulk convert for all four regions (x, Wqkv, Wproj, mask).
// Region selected by blockIdx.x; mask region scaled by log2e.
// ---------------------------------------------------------------------------
__global__ __launch_bounds__(256)
void cvt_all(const float* __restrict__ x,  bf16* __restrict__ xb,
             const float* __restrict__ wq, bf16* __restrict__ wqb,
             const float* __restrict__ wp, bf16* __restrict__ wpb,
             const float* __restrict__ mk, bf16* __restrict__ mkb)
{
  const int bi = blockIdx.x;
  const float* src; bf16* dst; float scale = 1.0f; size_t off;
  if (bi < 4096)      { src = x;  dst = xb;  off = (size_t)bi * 2048; }
  else if (bi < 5632) { src = wq; dst = wqb; off = (size_t)(bi - 4096) * 2048; }
  else if (bi < 6144) { src = wp; dst = wpb; off = (size_t)(bi - 5632) * 2048; }
  else { src = mk; dst = mkb; off = (size_t)(bi - 6144) * 2048;
         scale = 1.4426950408889634f; }
  const size_t i = off + (size_t)threadIdx.x * 8;
  f32x4 a = *(const f32x4*)(src + i) * scale;
  f32x4 b = *(const f32x4*)(src + i + 4) * scale;
  *(bf16x8*)(dst + i) = cvt8(a, b);
}

// ---------------------------------------------------------------------------
// GEMM, m97 structure (round-13, unchanged): C[m][n] = sum_k A[m][k]*B[n][k].
// MODE 0: LDS-retile epilogue, b128 stores: Q linear, K d-swizzled,
//         VT n-swizzled (no rope here).
// MODE 1: + bias -> out fp32 [8192][1024].
// ---------------------------------------------------------------------------
template<int MODE>
__global__ __launch_bounds__(256)
void gemm_bt(const bf16* __restrict__ A, const bf16* __restrict__ B,
             void* __restrict__ O0, bf16* __restrict__ O1, bf16* __restrict__ O2,
             const float* __restrict__ bias)
{
  constexpr int K = 1024;
  __shared__ __attribute__((aligned(16))) bf16 S[MODE == 0 ? 17408 : 16384];
  bf16* As = S;
  bf16* Bs = S + 128 * 64;
  const int tid = threadIdx.x, lane = tid & 63, wid = tid >> 6;
  const int m0 = blockIdx.x * 128, n0 = blockIdx.y * 128;
  const int wm = (wid >> 1) * 64, wn = (wid & 1) * 64;
  const int l15 = lane & 15, lg = lane >> 4;

  f32x4 acc[4][4] = {};

  for (int k0 = 0; k0 < K; k0 += 64) {
#pragma unroll
    for (int c = 0; c < 4; ++c) {
      const int seg = wid * 4 + c;
      const int o = seg * 1024 + lane * 16;   // byte offset in 16KB tile
      const int row = o >> 7, colb = o & 127; // 128B per row (64 bf16)
      gload16((const char*)B + (((size_t)(n0 + row) * K + k0) << 1) + colb,
              (char*)Bs + seg * 1024);
      gload16((const char*)A + (((size_t)(m0 + row) * K + k0) << 1) + colb,
              (char*)As + seg * 1024);
    }
    __syncthreads();

    bf16x8 af[4][2], bb[4][2];
#pragma unroll
    for (int i = 0; i < 4; ++i)
#pragma unroll
      for (int kk = 0; kk < 2; ++kk) {
        af[i][kk] = *(const bf16x8*)(As + (wm + i * 16 + l15) * 64 + kk * 32 + lg * 8);
        bb[i][kk] = *(const bf16x8*)(Bs + (wn + i * 16 + l15) * 64 + kk * 32 + lg * 8);
      }
#pragma unroll
    for (int mi = 0; mi < 4; ++mi)
#pragma unroll
      for (int ni = 0; ni < 4; ++ni)
#pragma unroll
        for (int kk = 0; kk < 2; ++kk)
          acc[mi][ni] = MFMA16(af[mi][kk], bb[ni][kk], acc[mi][ni]);
    __syncthreads();
  }

  if (MODE == 0) {
    // ---- LDS re-tile epilogue: acc -> T[n_local][c] (bf16, stride 136) ----
    bf16* T = S;
#pragma unroll
    for (int mi = 0; mi < 4; ++mi)
#pragma unroll
      for (int ni = 0; ni < 4; ++ni)
#pragma unroll
        for (int r = 0; r < 4; ++r)
          T[(wm + mi * 16 + lg * 4 + r) * 136 + wn + ni * 16 + l15] =
              (bf16)acc[mi][ni][r];
    __syncthreads();

    const int s = n0 >> 10;            // 0:Q 1:K 2:V (uniform per block)
    const int h0 = (n0 >> 6) & 15;
    if (s < 2) {
      // Q/K: rows of T are [n][d] -> b128 reads + b128 stores
      bf16* dst = (s == 0) ? (bf16*)O0 : O1;
      const int nl = tid >> 1, ch = (tid & 1) * 64;
      const int row = m0 + nl, b = row >> 11, n = row & 2047;
#pragma unroll
      for (int j = 0; j < 8; ++j) {
        const int c = ch + j * 8;
        const int h = h0 + (c >> 6), d0 = c & 63;
        const int ds = (s == 1) ? (d0 ^ ((n & 7) << 3)) : d0;
        *(int4v*)(dst + (((size_t)(b * 16 + h) * 2048) + n) * 64 + ds) =
            *(const int4v*)(T + nl * 136 + c);
      }
    } else {
      // V: gather 8-elem columns of T -> b128 stores along (pre-swizzled) n
      const int c = tid >> 1, nh = (tid & 1) * 64;
      const int h = h0 + (c >> 6), d = c & 63;
      const int b = m0 >> 11, nb = m0 & 2047;
#pragma unroll
      for (int j = 0; j < 8; ++j) {
        const int n8 = nh + j * 8;
        __attribute__((aligned(16))) bf16 tmp[8];
#pragma unroll
        for (int i = 0; i < 8; ++i) tmp[i] = T[(n8 + i) * 136 + c];
        const int ng = nb + n8;
        const int nswz = (ng & ~63) | ((ng & 63) ^ ((d & 7) << 3));
        *(int4v*)(O2 + ((size_t)(b * 16 + h) * 64 + d) * 2048 + nswz) =
            *(const int4v*)tmp;
      }
    }
  } else {
#pragma unroll
    for (int mi = 0; mi < 4; ++mi)
#pragma unroll
      for (int ni = 0; ni < 4; ++ni)
#pragma unroll
        for (int r = 0; r < 4; ++r) {
          const int row = m0 + wm + mi * 16 + lg * 4 + r;
          const int col = n0 + wn + ni * 16 + l15;
          ((float*)O0)[(size_t)row * 1024 + col] = acc[mi][ni][r] + bias[col];
        }
  }
}

// ---------------------------------------------------------------------------
// RoPE in place on Q (linear) and K (d-swizzled). cos/sin fp32 [B][N][32].
// Q additionally pre-scaled by SCALE*log2e so attention softmax is exp2(s).
// For K: stored 8-group g at row n holds logical group g^(n&7).
// (Bit-identical to the round-13 passing version.)
// ---------------------------------------------------------------------------
__global__ __launch_bounds__(256)
void rope_k(bf16* __restrict__ Q, bf16* __restrict__ K,
            const float* __restrict__ C, const float* __restrict__ S)
{
  constexpr float SL = 0.125f * 1.4426950408889634f;
  const int gid = blockIdx.x * 256 + threadIdx.x;
  const int part = gid & 3;
  const int rowid = gid >> 2;
  const int n = rowid & 2047;
  const int b = rowid >> 15;
  const size_t cb0 = ((size_t)(b * 2048 + n)) * 32;

  __attribute__((aligned(16))) bf16 buf[16];

  // ---- Q (linear layout) ----
  {
    float cf[8], sf[8];
    *(f32x4*)cf = *(const f32x4*)(C + cb0 + part * 8);
    *(f32x4*)(cf + 4) = *(const f32x4*)(C + cb0 + part * 8 + 4);
    *(f32x4*)sf = *(const f32x4*)(S + cb0 + part * 8);
    *(f32x4*)(sf + 4) = *(const f32x4*)(S + cb0 + part * 8 + 4);

    bf16* qp = Q + (size_t)rowid * 64 + part * 16;
    *(int4v*)buf = *(const int4v*)qp;
    *(int4v*)(buf + 8) = *(const int4v*)(qp + 8);
#pragma unroll
    for (int j = 0; j < 8; ++j) {
      const float t0 = (float)buf[2 * j], t1 = (float)buf[2 * j + 1];
      buf[2 * j]     = (bf16)((t0 * cf[j] - t1 * sf[j]) * SL);
      buf[2 * j + 1] = (bf16)((t0 * sf[j] + t1 * cf[j]) * SL);
    }
    *(int4v*)qp = *(int4v*)buf;
    *(int4v*)(qp + 8) = *(int4v*)(buf + 8);
  }

  // ---- K (d-swizzled layout) ----
  {
    const int sg = n & 7;
    bf16* kp = K + (size_t)rowid * 64 + part * 16;
    *(int4v*)buf = *(const int4v*)kp;
    *(int4v*)(buf + 8) = *(const int4v*)(kp + 8);
#pragma unroll
    for (int gi = 0; gi < 2; ++gi) {
      const int lg = (2 * part + gi) ^ sg;      // logical 8-group
      const f32x4 c4 = *(const f32x4*)(C + cb0 + lg * 4);
      const f32x4 s4 = *(const f32x4*)(S + cb0 + lg * 4);
#pragma unroll
      for (int m = 0; m < 4; ++m) {
        const float t0 = (float)buf[gi * 8 + 2 * m];
        const float t1 = (float)buf[gi * 8 + 2 * m + 1];
        buf[gi * 8 + 2 * m]     = (bf16)(t0 * c4[m] - t1 * s4[m]);
        buf[gi * 8 + 2 * m + 1] = (bf16)(t0 * s4[m] + t1 * c4[m]);
      }
    }
    *(int4v*)kp = *(int4v*)buf;
    *(int4v*)(kp + 8) = *(int4v*)(buf + 8);
  }
}

// ---------------------------------------------------------------------------
// Flash attention: round-12 core (mfma_32x32x16, swapped QK^T, mask as MFMA
// C-init, exp2 softmax, in-register P via cvt_pk+permlane, setprio, 2-phase
// gload_lds double-buffer with pre-swizzled ws sources) at 8 WAVES/BLOCK:
// 256 q-rows per block -> K/V staging traffic halves. Grid (64, 8).
// MM=1: mask bf16*log2e with cur/nxt register rotation; MM=0: fp32 in-tile.
// ---------------------------------------------------------------------------
template<int MM>
__global__ __launch_bounds__(512, 4)
void attn_k(const bf16* __restrict__ Q, const bf16* __restrict__ K,
            const bf16* __restrict__ VT, const void* __restrict__ Mv,
            bf16* __restrict__ O)
{
  constexpr float LOG2E = 1.4426950408889634f;
  constexpr int NT = 32;
  // 2 K|V buffer sets (16384 bf16); epilogue overlay 8 x 2304 = 18432 bf16
  __shared__ __attribute__((aligned(16))) bf16 SH[18432];

  const int tid = threadIdx.x, lane = tid & 63, w = tid >> 6;
  const int bh = blockIdx.x;
  const int q0 = blockIdx.y * 256;
  const int b = bh >> 4, h = bh & 15;
  const int l31 = lane & 31, hi = lane >> 5;
  const int swz = (l31 & 7) << 3;

  const bf16* Qb = Q + (size_t)bh * 2048 * 64;
  const bf16* Kb = K + (size_t)bh * 2048 * 64;
  const bf16* Vb = VT + (size_t)bh * 64 * 2048;
  const float* Mqf = (const float*)Mv + (size_t)(q0 + w * 32 + l31) * 2048;
  const bf16*  Mqb = (const bf16*)Mv  + (size_t)(q0 + w * 32 + l31) * 2048;

  bf16x8 qf[4];
  {
    const bf16* qr = Qb + (size_t)(q0 + w * 32 + l31) * 64 + 8 * hi;
#pragma unroll
    for (int j = 0; j < 4; ++j) qf[j] = *(const bf16x8*)(qr + 16 * j);
  }

  f32x16 o[2] = {{0,0,0,0,0,0,0,0,0,0,0,0,0,0,0,0},
                 {0,0,0,0,0,0,0,0,0,0,0,0,0,0,0,0}};
  float li = 0.f;

  // 512 threads stage 16KB/tile: one 16B K-slot + one 16B V-slot per thread;
  // LDS dst = wave-uniform base + lane*16 (linear; ws sources pre-swizzled)
#define STAGE_TILE(KVN, BUFSEL) do {                                          \
    bf16* Ktn = SH + (BUFSEL) * 8192;                                         \
    bf16* Vtn = Ktn + 4096;                                                   \
    gload16((const char*)Kb + (((size_t)(KVN) * 64 + tid * 8) << 1),          \
            (char*)Ktn + w * 1024);                                           \
    gload16((const char*)Vb +                                                 \
                (((size_t)(tid >> 3) * 2048 + (KVN) + (tid & 7) * 8) << 1),   \
            (char*)Vtn + w * 1024);                                           \
  } while (0)

  bf16x4 mkb_cur[2][4], mkb_nxt[2][4];

  STAGE_TILE(0, 0);
  if (MM == 1) {
#pragma unroll
    for (int sub = 0; sub < 2; ++sub)
#pragma unroll
      for (int rg = 0; rg < 4; ++rg)
        mkb_cur[sub][rg] = *(const bf16x4*)(Mqb + 32 * sub + 8 * rg + 4 * hi);
  }
  __syncthreads();

  for (int t = 0; t < NT; ++t) {
    bf16* Kt = SH + (t & 1) * 8192;
    bf16* Vt = Kt + 4096;

    if (t + 1 < NT) {
      const int kvn = (t + 1) * 64;
      STAGE_TILE(kvn, (t + 1) & 1);
      if (MM == 1) {
#pragma unroll
        for (int sub = 0; sub < 2; ++sub)
#pragma unroll
          for (int rg = 0; rg < 4; ++rg)
            mkb_nxt[sub][rg] = *(const bf16x4*)(Mqb + kvn + 32 * sub + 8 * rg + 4 * hi);
      }
    }
    f32x4 mkf[2][4];
    if (MM == 0) {
      const int kv0 = t * 64;
#pragma unroll
      for (int sub = 0; sub < 2; ++sub)
#pragma unroll
        for (int rg = 0; rg < 4; ++rg)
          mkf[sub][rg] = *(const f32x4*)(Mqf + kv0 + 32 * sub + 8 * rg + 4 * hi);
    }

#pragma unroll
    for (int sub = 0; sub < 2; ++sub) {
      f32x16 s;
#pragma unroll
      for (int rg = 0; rg < 4; ++rg)
#pragma unroll
        for (int i = 0; i < 4; ++i)
          s[4 * rg + i] = (MM == 0) ? mkf[sub][rg][i] * LOG2E
                                    : (float)mkb_cur[sub][rg][i];
      __builtin_amdgcn_s_setprio(1);
#pragma unroll
      for (int j = 0; j < 4; ++j) {
        const bf16x8 kf = *(const bf16x8*)(
            Kt + (sub * 32 + l31) * 64 + ((16 * j + 8 * hi) ^ swz));
        s = MFMA32(kf, qf[j], s);
      }
      __builtin_amdgcn_s_setprio(0);

      float rs = 0.f;
#pragma unroll
      for (int e = 0; e < 16; ++e) {
        const float p = __builtin_exp2f(s[e]);
        s[e] = p;
        rs += p;
      }
      rs += __shfl_xor(rs, 32);
      li += rs;

      uint32_t pk0, pk1, pk2, pk3, pk4, pk5, pk6, pk7;
      asm("v_cvt_pk_bf16_f32 %0, %1, %2" : "=v"(pk0) : "v"(s[0]),  "v"(s[1]));
      asm("v_cvt_pk_bf16_f32 %0, %1, %2" : "=v"(pk1) : "v"(s[2]),  "v"(s[3]));
      asm("v_cvt_pk_bf16_f32 %0, %1, %2" : "=v"(pk2) : "v"(s[4]),  "v"(s[5]));
      asm("v_cvt_pk_bf16_f32 %0, %1, %2" : "=v"(pk3) : "v"(s[6]),  "v"(s[7]));
      asm("v_cvt_pk_bf16_f32 %0, %1, %2" : "=v"(pk4) : "v"(s[8]),  "v"(s[9]));
      asm("v_cvt_pk_bf16_f32 %0, %1, %2" : "=v"(pk5) : "v"(s[10]), "v"(s[11]));
      asm("v_cvt_pk_bf16_f32 %0, %1, %2" : "=v"(pk6) : "v"(s[12]), "v"(s[13]));
      asm("v_cvt_pk_bf16_f32 %0, %1, %2" : "=v"(pk7) : "v"(s[14]), "v"(s[15]));
      asm("v_permlane32_swap_b32 %0, %1" : "+v"(pk0), "+v"(pk2));
      asm("v_permlane32_swap_b32 %0, %1" : "+v"(pk1), "+v"(pk3));
      asm("v_permlane32_swap_b32 %0, %1" : "+v"(pk4), "+v"(pk6));
      asm("v_permlane32_swap_b32 %0, %1" : "+v"(pk5), "+v"(pk7));
      uint32_t pau[2][4] = {{pk0, pk1, pk2, pk3}, {pk4, pk5, pk6, pk7}};
      bf16x8 pa[2];
      __builtin_memcpy(&pa[0], pau[0], 16);
      __builtin_memcpy(&pa[1], pau[1], 16);

      __builtin_amdgcn_s_setprio(1);
#pragma unroll
      for (int kh = 0; kh < 2; ++kh)
#pragma unroll
        for (int dblk = 0; dblk < 2; ++dblk) {
          const bf16x8 vf = *(const bf16x8*)(
              Vt + (dblk * 32 + l31) * 64 + ((sub * 32 + kh * 16 + 8 * hi) ^ swz));
          o[dblk] = MFMA32(vf, pa[kh], o[dblk]);
        }
      __builtin_amdgcn_s_setprio(0);
    }

    if (MM == 1 && t + 1 < NT) {
#pragma unroll
      for (int sub = 0; sub < 2; ++sub)
#pragma unroll
        for (int rg = 0; rg < 4; ++rg)
          mkb_cur[sub][rg] = mkb_nxt[sub][rg];
    }
    __syncthreads();
  }
#undef STAGE_TILE

  // epilogue: normalize (lane-local), transpose via LDS, b128 stores.
  const float inv = 1.f / li;
  bf16* ow = SH + w * 2304;
#pragma unroll
  for (int dblk = 0; dblk < 2; ++dblk)
#pragma unroll
    for (int rg = 0; rg < 4; ++rg)
      *(bf16x4*)(ow + l31 * 72 + dblk * 32 + 8 * rg + 4 * hi) =
          cvt4s(o[dblk][4 * rg] * inv, o[dblk][4 * rg + 1] * inv,
                o[dblk][4 * rg + 2] * inv, o[dblk][4 * rg + 3] * inv);
  asm volatile("s_waitcnt lgkmcnt(0)" ::: "memory");
  __builtin_amdgcn_sched_barrier(0);
#pragma unroll
  for (int p = 0; p < 4; ++p) {
    const int row = p * 8 + (lane >> 3);
    const int n = q0 + w * 32 + row;
    const int4v v = *(const int4v*)(ow + row * 72 + (lane & 7) * 8);
    *(int4v*)(O + ((size_t)b * 2048 + n) * 1024 + h * 64 + (lane & 7) * 8) = v;
  }
}

// ---------------------------------------------------------------------------
extern "C" void kernel_launch(void* const* d_in, const int* in_sizes, int n_in,
                              void* d_out, int out_size, void* d_ws, size_t ws_size,
                              hipStream_t stream)
{
  (void)in_sizes; (void)n_in; (void)out_size;
  const float* x     = (const float*)d_in[0];
  const float* fcos  = (const float*)d_in[1];
  const float* fsin  = (const float*)d_in[2];
  const float* mask  = (const float*)d_in[3];
  const float* wqkv  = (const float*)d_in[4];
  const float* wproj = (const float*)d_in[5];
  const float* bproj = (const float*)d_in[6];
  float* out = (float*)d_out;

  const size_t SZ  = (size_t)64 * 2048 * 64 * 2;           // 16.78 MB
  const size_t WQB = (size_t)3072 * 1024 * 2;              // 6.29 MB
  const size_t WPB = (size_t)1024 * 1024 * 2;              // 2.10 MB
  const size_t MKB = (size_t)2048 * 2048 * 2;              // 8.39 MB (bf16 mask)
  const size_t BASE = 4 * SZ + WQB + WPB;                  // 75.5 MB (proven)
  if (ws_size < BASE) return;                              // fail loudly
  char* ws = (char*)d_ws;
  bf16* Qr  = (bf16*)(ws);
  bf16* Kr  = (bf16*)(ws + SZ);
  bf16* VT  = (bf16*)(ws + 2 * SZ);
  bf16* Ob  = (bf16*)(ws + 3 * SZ);   // doubles as bf16(x) before attn runs
  bf16* Wqb = (bf16*)(ws + 4 * SZ);
  bf16* Wpb = (bf16*)(ws + 4 * SZ + WQB);
  bf16* Mb  = (bf16*)(ws + BASE);
  const bool useMb = (ws_size >= BASE + MKB);
  bf16* Xb = Ob;  // x-bf16 lives in the Ob slot (dead until attn)

  cvt_all<<<useMb ? 8192 : 6144, 256, 0, stream>>>(x, Xb, wqkv, Wqb,
                                                   wproj, Wpb, mask, Mb);
  gemm_bt<0><<<dim3(64, 24), 256, 0, stream>>>(Xb, Wqb, Qr, Kr, VT, nullptr);
  rope_k<<<2048, 256, 0, stream>>>(Qr, Kr, fcos, fsin);
  if (useMb)
    attn_k<1><<<dim3(64, 8), 512, 0, stream>>>(Qr, Kr, VT, Mb, Ob);
  else
    attn_k<0><<<dim3(64, 8), 512, 0, stream>>>(Qr, Kr, VT, mask, Ob);
  gemm_bt<1><<<dim3(64, 8), 256, 0, stream>>>(Ob, Wpb, out, nullptr, nullptr,
                                              bproj);
}